// Round 2
// baseline (255.598 us; speedup 1.0000x reference)
//
#include <hip/hip_runtime.h>
#include <stdint.h>

typedef __attribute__((ext_vector_type(8))) short short8;
typedef __attribute__((ext_vector_type(4))) float floatx4;

static inline size_t align256(size_t x) { return (x + 255) & ~size_t(255); }

__device__ __forceinline__ unsigned short f2bf(float f) {
    unsigned u = __float_as_uint(f);
    u += 0x7fff + ((u >> 16) & 1);     // round-to-nearest-even
    return (unsigned short)(u >> 16);
}
__device__ __forceinline__ unsigned pack_bf16(float a, float b) {
    return (unsigned)f2bf(a) | ((unsigned)f2bf(b) << 16);
}
__device__ __forceinline__ float bf_lo(unsigned u) { return __uint_as_float(u << 16); }
__device__ __forceinline__ float bf_hi(unsigned u) { return __uint_as_float(u & 0xffff0000u); }

#define CH 2048      // edges per block in deg/fill

// per-block edge dtype self-detection: int32 data read as int64 pairs gives
// out-of-range values with prob ~1 per sample; 256 samples => certain.
__device__ __forceinline__ bool detect_i32(const void* eidx, int E, int t) {
    const long long* e64 = (const long long*)eidx;
    int nchk = E < 256 ? E : 256;
    long long v = e64[t % nchk];
    int bad = (v < 0 || v > 0x7fffffffLL) ? 1 : 0;
    return __syncthreads_or(bad) != 0;
}

// ---- init: zero degree counters / scan bookkeeping + transpose weights ----
__global__ __launch_bounds__(256) void k_init(int* __restrict__ cnt, int N,
        int* __restrict__ tb, long long* __restrict__ partials, int NT,
        const float* __restrict__ W1, const float* __restrict__ W2,
        unsigned short* __restrict__ w1t, unsigned short* __restrict__ w2t,
        int K1, int M1, int K2, int M2) {
    int gid = blockIdx.x * 256 + threadIdx.x;
    int tot = gridDim.x * 256;
    for (int i = gid; i < N; i += tot) cnt[i] = 0;
    if (gid == 0) *tb = 0;
    for (int i = gid; i < NT; i += tot) partials[i] = 0;
    for (int j = gid; j < K1 * M1; j += tot) {
        int k = j / M1, n = j % M1;
        w1t[(size_t)n * K1 + k] = f2bf(W1[j]);
    }
    for (int j = gid; j < K2 * M2; j += tot) {
        int k = j / M2, n = j % M2;
        w2t[(size_t)n * K2 + k] = f2bf(W2[j]);
    }
}

// ---- degree histogram: global atomics on cnt[dst] ----
__global__ __launch_bounds__(256) void k_deg(const void* __restrict__ eidx, int E,
                                             int* __restrict__ cnt) {
    const int t = threadIdx.x, B = blockIdx.x;
    const int e0 = B * CH;
    const int e1 = (e0 + CH < E) ? e0 + CH : E;
    const bool i32 = detect_i32(eidx, E, t);
    const int* e32 = (const int*)eidx;
    const long long* e64 = (const long long*)eidx;
    for (int e = e0 + t; e < e1; e += 256) {
        int d = i32 ? e32[(size_t)E + e] : (int)e64[(size_t)E + e];
        atomicAdd(&cnt[d], 1);
    }
}

// ---- decoupled-lookback exclusive scan of cnt -> rs, cursor; dinv ----
// 1024 elements per tile; ticket-ordered blocks so lookback cannot deadlock.
__device__ __forceinline__ long long pack_sv(int status, int value) {
    return ((long long)status << 32) | (unsigned)value;
}
__global__ __launch_bounds__(256) void k_scan(const int* __restrict__ cnt,
        int* __restrict__ rs, int* __restrict__ cursor, float* __restrict__ dinv,
        int N, int E, int* __restrict__ tb, long long* __restrict__ partials, int NT) {
    __shared__ int s_tile;
    __shared__ int wsum[4];
    __shared__ int s_excl;
    const int t = threadIdx.x, lane = t & 63, w = t >> 6;
    if (t == 0) s_tile = atomicAdd(tb, 1);
    __syncthreads();
    const int tile = s_tile;
    const int idx = tile * 1024 + t * 4;
    int v0 = 0, v1 = 0, v2 = 0, v3 = 0;
    if (idx + 4 <= N) {
        int4 q = *(const int4*)&cnt[idx];
        v0 = q.x; v1 = q.y; v2 = q.z; v3 = q.w;
    } else {
        if (idx + 0 < N) v0 = cnt[idx + 0];
        if (idx + 1 < N) v1 = cnt[idx + 1];
        if (idx + 2 < N) v2 = cnt[idx + 2];
        if (idx + 3 < N) v3 = cnt[idx + 3];
    }
    int tsum = v0 + v1 + v2 + v3;
    int incl = tsum;
    #pragma unroll
    for (int off = 1; off < 64; off <<= 1) {
        int nbr = __shfl_up(incl, off, 64);
        if (lane >= off) incl += nbr;
    }
    if (lane == 63) wsum[w] = incl;
    __syncthreads();
    int woff = 0;
    for (int j = 0; j < w; ++j) woff += wsum[j];
    int agg = wsum[0] + wsum[1] + wsum[2] + wsum[3];
    int texcl = woff + incl - tsum;      // thread's exclusive offset within tile
    if (t == 0) {
        if (tile == 0) {
            __hip_atomic_store(&partials[0], pack_sv(2, agg),
                               __ATOMIC_RELEASE, __HIP_MEMORY_SCOPE_AGENT);
            s_excl = 0;
            rs[N] = E;                    // total (scan of cnt sums to E)
        } else {
            __hip_atomic_store(&partials[tile], pack_sv(1, agg),
                               __ATOMIC_RELEASE, __HIP_MEMORY_SCOPE_AGENT);
            int excl = 0;
            for (int p = tile - 1; p >= 0; ) {
                long long pv;
                do {
                    pv = __hip_atomic_load(&partials[p],
                                           __ATOMIC_ACQUIRE, __HIP_MEMORY_SCOPE_AGENT);
                } while ((int)(pv >> 32) == 0);
                excl += (int)(unsigned)(pv & 0xffffffffLL);
                if ((int)(pv >> 32) == 2) break;
                --p;
            }
            __hip_atomic_store(&partials[tile], pack_sv(2, excl + agg),
                               __ATOMIC_RELEASE, __HIP_MEMORY_SCOPE_AGENT);
            s_excl = excl;
        }
    }
    __syncthreads();
    int ex = s_excl + texcl;
    if (idx + 0 < N) { rs[idx + 0] = ex; cursor[idx + 0] = ex; dinv[idx + 0] = rsqrtf((float)v0 + 1.0f); ex += v0; }
    if (idx + 1 < N) { rs[idx + 1] = ex; cursor[idx + 1] = ex; dinv[idx + 1] = rsqrtf((float)v1 + 1.0f); ex += v1; }
    if (idx + 2 < N) { rs[idx + 2] = ex; cursor[idx + 2] = ex; dinv[idx + 2] = rsqrtf((float)v2 + 1.0f); ex += v2; }
    if (idx + 3 < N) { rs[idx + 3] = ex; cursor[idx + 3] = ex; dinv[idx + 3] = rsqrtf((float)v3 + 1.0f); }
}

// ---- fill: slot = cursor[dst]++ ; esrc[slot] = src ----
__global__ __launch_bounds__(256) void k_fill(const void* __restrict__ eidx, int E,
                                              int* __restrict__ cursor,
                                              int* __restrict__ esrc) {
    const int t = threadIdx.x, B = blockIdx.x;
    const int e0 = B * CH;
    const int e1 = (e0 + CH < E) ? e0 + CH : E;
    const bool i32 = detect_i32(eidx, E, t);
    const int* e32 = (const int*)eidx;
    const long long* e64 = (const long long*)eidx;
    for (int e = e0 + t; e < e1; e += 256) {
        int s, d;
        if (i32) { s = e32[e]; d = e32[(size_t)E + e]; }
        else     { s = (int)e64[e]; d = (int)e64[(size_t)E + e]; }
        int slot = atomicAdd(&cursor[d], 1);
        esrc[slot] = s;
    }
}

// ============================================================================
// bf16 MFMA GEMM, tile 64 rows x BN cols (BN == M), K=128 one LDS stage.
// AF32: A is fp32, converted during staging. Epilogue folds dinv.
// ============================================================================
template<int BN, bool AF32>
__global__ __launch_bounds__(256, 3) void k_gemm(
        const void* __restrict__ Av, const unsigned short* __restrict__ Bt,
        const float* __restrict__ dinv, unsigned short* __restrict__ C,
        int N, int M) {
    constexpr int LD = 136;               // 128 + 8 u16 pad
    __shared__ unsigned short As[64 * LD];
    __shared__ unsigned short Bs[BN * LD];
    const int tid = threadIdx.x;
    const int wave = tid >> 6, lane = tid & 63;
    const int q = lane >> 4, tm = lane & 15;
    const int row0 = blockIdx.x * 64;

    {   // stage Bt rows [0,BN)
        const uint4* Bg = (const uint4*)Bt;
        #pragma unroll
        for (int it = 0; it < BN / 16; ++it) {
            int i = tid + it * 256;
            int r = i >> 4, o = i & 15;
            *(uint4*)&Bs[r * LD + o * 8] = Bg[(size_t)r * 16 + o];
        }
    }
    if (AF32) {   // stage A rows with inline fp32->bf16
        const float4* Ag = (const float4*)Av;
        #pragma unroll
        for (int it = 0; it < 8; ++it) {
            int i = tid + it * 256;
            int r = i >> 5, o = i & 31;
            int row = row0 + r;
            float4 v = make_float4(0.f, 0.f, 0.f, 0.f);
            if (row < N) v = Ag[(size_t)row * 32 + o];
            uint2 pk;
            pk.x = pack_bf16(v.x, v.y);
            pk.y = pack_bf16(v.z, v.w);
            *(uint2*)&As[r * LD + o * 4] = pk;
        }
    } else {      // stage bf16 A rows
        const uint4* Ag = (const uint4*)Av;
        #pragma unroll
        for (int it = 0; it < 4; ++it) {
            int i = tid + it * 256;
            int r = i >> 4, o = i & 15;
            int row = row0 + r;
            uint4 v = make_uint4(0, 0, 0, 0);
            if (row < N) v = Ag[(size_t)row * 16 + o];
            *(uint4*)&As[r * LD + o * 8] = v;
        }
    }
    __syncthreads();

    constexpr int NG = BN / 16;
    floatx4 acc[NG];
    #pragma unroll
    for (int g = 0; g < NG; ++g) acc[g] = (floatx4){0.f, 0.f, 0.f, 0.f};

    const int arow = wave * 16 + tm;
    #pragma unroll
    for (int kc = 0; kc < 4; ++kc) {
        short8 af = *(const short8*)&As[arow * LD + kc * 32 + q * 8];
        #pragma unroll
        for (int g = 0; g < NG; ++g) {
            short8 bf = *(const short8*)&Bs[(g * 16 + tm) * LD + kc * 32 + q * 8];
            acc[g] = __builtin_amdgcn_mfma_f32_16x16x32_bf16(af, bf, acc[g], 0, 0, 0);
        }
    }

    float dv[4];
    #pragma unroll
    for (int r = 0; r < 4; ++r) {
        int row = row0 + wave * 16 + q * 4 + r;
        dv[r] = (row < N) ? dinv[row] : 0.f;
    }
    #pragma unroll
    for (int g = 0; g < NG; ++g) {
        #pragma unroll
        for (int r = 0; r < 4; ++r) {
            int row = row0 + wave * 16 + q * 4 + r;
            if (row < N) C[(size_t)row * M + g * 16 + tm] = f2bf(dv[r] * acc[g][r]);
        }
    }
}

// ---- aggregation, F=128: half-wave per edge, dwordx2 gathers (512 B/instr) ----
__global__ __launch_bounds__(256) void k_agg128(const unsigned* __restrict__ Hb,
        const float* __restrict__ dinv, const int* __restrict__ rs,
        const int* __restrict__ esrc, const float* __restrict__ bias,
        uint2* __restrict__ out, int N) {
    int wid = (blockIdx.x * 256 + threadIdx.x) >> 6;
    if (wid >= N) return;
    int l = threadIdx.x & 63;
    int hi = l >> 5;            // half-wave id: which edge of the pair
    int q  = l & 31;            // uint2 index within the 256 B row
    const uint2* H2 = (const uint2*)Hb;      // row stride = 32 uint2
    float di = dinv[wid];
    float a0 = 0.f, a1 = 0.f, a2 = 0.f, a3 = 0.f;
    int k = rs[wid], kend = rs[wid + 1];
    for (; k + 8 <= kend; k += 8) {          // 4 pairs in flight
        int s[4];
        #pragma unroll
        for (int j = 0; j < 4; ++j) s[j] = esrc[k + 2 * j + hi];
        uint2 g[4];
        #pragma unroll
        for (int j = 0; j < 4; ++j) g[j] = H2[(size_t)s[j] * 32 + q];
        #pragma unroll
        for (int j = 0; j < 4; ++j) {
            a0 += bf_lo(g[j].x); a1 += bf_hi(g[j].x);
            a2 += bf_lo(g[j].y); a3 += bf_hi(g[j].y);
        }
    }
    if (k + 4 <= kend) {                     // 2 pairs
        int s[2];
        #pragma unroll
        for (int j = 0; j < 2; ++j) s[j] = esrc[k + 2 * j + hi];
        uint2 g[2];
        #pragma unroll
        for (int j = 0; j < 2; ++j) g[j] = H2[(size_t)s[j] * 32 + q];
        #pragma unroll
        for (int j = 0; j < 2; ++j) {
            a0 += bf_lo(g[j].x); a1 += bf_hi(g[j].x);
            a2 += bf_lo(g[j].y); a3 += bf_hi(g[j].y);
        }
        k += 4;
    }
    if (k + 2 <= kend) {                     // 1 pair
        int s = esrc[k + hi];
        uint2 g = H2[(size_t)s * 32 + q];
        a0 += bf_lo(g.x); a1 += bf_hi(g.x);
        a2 += bf_lo(g.y); a3 += bf_hi(g.y);
        k += 2;
    }
    if (k < kend && hi == 0) {               // odd last edge: low half only
        int s = esrc[k];
        uint2 g = H2[(size_t)s * 32 + q];
        a0 += bf_lo(g.x); a1 += bf_hi(g.x);
        a2 += bf_lo(g.y); a3 += bf_hi(g.y);
    }
    a0 += __shfl_xor(a0, 32, 64);
    a1 += __shfl_xor(a1, 32, 64);
    a2 += __shfl_xor(a2, 32, 64);
    a3 += __shfl_xor(a3, 32, 64);
    uint2 sr = H2[(size_t)wid * 32 + q];     // self row (already dinv-scaled)
    a0 += bf_lo(sr.x); a1 += bf_hi(sr.x);
    a2 += bf_lo(sr.y); a3 += bf_hi(sr.y);
    float4 b = ((const float4*)bias)[q];
    float o0 = fmaxf(fmaf(di, a0, b.x), 0.f);   // layer 1: ReLU
    float o1 = fmaxf(fmaf(di, a1, b.y), 0.f);
    float o2 = fmaxf(fmaf(di, a2, b.z), 0.f);
    float o3 = fmaxf(fmaf(di, a3, b.w), 0.f);
    if (hi == 0) {
        uint2 pk;
        pk.x = pack_bf16(o0, o1);
        pk.y = pack_bf16(o2, o3);
        out[(size_t)wid * 32 + q] = pk;
    }
}

// ---- aggregation, F=64: half-wave per edge, dword gathers (256 B/instr) ----
__global__ __launch_bounds__(256) void k_agg64(const unsigned short* __restrict__ Hb,
        const float* __restrict__ dinv, const int* __restrict__ rs,
        const int* __restrict__ esrc, const float* __restrict__ bias,
        float2* __restrict__ out, int N) {
    int wid = (blockIdx.x * 256 + threadIdx.x) >> 6;
    if (wid >= N) return;
    int l = threadIdx.x & 63;
    int hi = l >> 5;            // which edge of the pair
    int q  = l & 31;            // dword index within the 128 B row
    const unsigned* H1 = (const unsigned*)Hb;    // row stride = 32 dwords
    float di = dinv[wid];
    float a0 = 0.f, a1 = 0.f;
    int k = rs[wid], kend = rs[wid + 1];
    for (; k + 8 <= kend; k += 8) {
        int s[4];
        #pragma unroll
        for (int j = 0; j < 4; ++j) s[j] = esrc[k + 2 * j + hi];
        unsigned g[4];
        #pragma unroll
        for (int j = 0; j < 4; ++j) g[j] = H1[(size_t)s[j] * 32 + q];
        #pragma unroll
        for (int j = 0; j < 4; ++j) { a0 += bf_lo(g[j]); a1 += bf_hi(g[j]); }
    }
    if (k + 4 <= kend) {
        int s[2];
        #pragma unroll
        for (int j = 0; j < 2; ++j) s[j] = esrc[k + 2 * j + hi];
        unsigned g[2];
        #pragma unroll
        for (int j = 0; j < 2; ++j) g[j] = H1[(size_t)s[j] * 32 + q];
        #pragma unroll
        for (int j = 0; j < 2; ++j) { a0 += bf_lo(g[j]); a1 += bf_hi(g[j]); }
        k += 4;
    }
    if (k + 2 <= kend) {
        int s = esrc[k + hi];
        unsigned g = H1[(size_t)s * 32 + q];
        a0 += bf_lo(g); a1 += bf_hi(g);
        k += 2;
    }
    if (k < kend && hi == 0) {
        unsigned g = H1[(size_t)esrc[k] * 32 + q];
        a0 += bf_lo(g); a1 += bf_hi(g);
    }
    a0 += __shfl_xor(a0, 32, 64);
    a1 += __shfl_xor(a1, 32, 64);
    unsigned sr = H1[(size_t)wid * 32 + q];
    a0 += bf_lo(sr); a1 += bf_hi(sr);
    float2 b = ((const float2*)bias)[q];
    if (hi == 0) {
        float2 o;
        o.x = fmaf(di, a0, b.x);
        o.y = fmaf(di, a1, b.y);
        out[(size_t)wid * 32 + q] = o;
    }
}

extern "C" void kernel_launch(void* const* d_in, const int* in_sizes, int n_in,
                              void* d_out, int out_size, void* d_ws, size_t ws_size,
                              hipStream_t stream) {
    const float* x  = (const float*)d_in[0];
    const void*  ei = d_in[1];
    const float* W1 = (const float*)d_in[2];
    const float* b1 = (const float*)d_in[3];
    const float* W2 = (const float*)d_in[4];
    const float* b2 = (const float*)d_in[5];

    int HID = in_sizes[3];            // 128
    int IN  = in_sizes[2] / HID;      // 128
    int OUT = in_sizes[4] / HID;      // 64
    int N   = in_sizes[0] / IN;       // 50000
    int E   = in_sizes[1] / 2;        // 800000
    int NC  = (E + CH - 1) / CH;      // edge chunks (391)
    int NT  = (N + 1023) >> 10;       // scan tiles (49)

    char* p = (char*)d_ws;
    int* cnt       = (int*)p;   p += align256((size_t)N * 4);
    int* rs_final  = (int*)p;   p += align256((size_t)(N + 1) * 4);
    int* cursor    = (int*)p;   p += align256((size_t)N * 4);
    float* dinv    = (float*)p; p += align256((size_t)N * 4);
    int* esrc      = (int*)p;   p += align256((size_t)E * 4);
    int* tb        = (int*)p;   p += align256(256);
    long long* partials = (long long*)p; p += align256((size_t)NT * 8);
    unsigned short* w1t = (unsigned short*)p; p += align256((size_t)HID * IN * 2);
    unsigned short* w2t = (unsigned short*)p; p += align256((size_t)OUT * HID * 2);
    unsigned short* hb  = (unsigned short*)p; p += align256((size_t)N * HID * 2);
    unsigned short* h1b = (unsigned short*)p; p += align256((size_t)N * HID * 2);
    unsigned short* h2b = (unsigned short*)p; p += align256((size_t)N * OUT * 2);

    // CSR build: init -> deg -> scan -> fill   (4 dispatches, was 6)
    k_init<<<96, 256, 0, stream>>>(cnt, N, tb, partials, NT,
                                   W1, W2, w1t, w2t, IN, HID, HID, OUT);
    k_deg<<<NC, 256, 0, stream>>>(ei, E, cnt);
    k_scan<<<NT, 256, 0, stream>>>(cnt, rs_final, cursor, dinv, N, E, tb, partials, NT);
    k_fill<<<NC, 256, 0, stream>>>(ei, E, cursor, esrc);

    // layer 1: hb = bf16(dinv * (x @ W1)) ; h1b = bf16(relu(dinv*sum + b1))
    k_gemm<128, true><<<(N + 63) / 64, 256, 0, stream>>>(x, w1t, dinv, hb, N, HID);
    k_agg128<<<(N + 3) / 4, 256, 0, stream>>>((unsigned*)hb, dinv, rs_final, esrc, b1,
                                              (uint2*)h1b, N);

    // layer 2: h2b = bf16(dinv * (h1b @ W2)) ; out = dinv*sum + b2
    k_gemm<64, false><<<(N + 63) / 64, 256, 0, stream>>>(h1b, w2t, dinv, h2b, N, OUT);
    k_agg64<<<(N + 3) / 4, 256, 0, stream>>>(h2b, dinv, rs_final, esrc, b2,
                                             (float2*)d_out, N);
}